// Round 5
// baseline (395.701 us; speedup 1.0000x reference)
//
#include <hip/hip_runtime.h>
#include <hip/hip_bf16.h>
#include <stdint.h>

// Problem constants (B,T,D,NH from reference)
#define NHh 16
#define Dm  1024
#define HD  64          // head dim = D/NH
#define Bb  4
#define Tt  4096
#define NCH 64          // chunks along T for the two-pass scans
#define CHL 64          // chunk length (NCH*CHL == Tt)

using bf16 = __hip_bfloat16;
typedef __attribute__((ext_vector_type(8))) short short8;   // 8 bf16 in 4 VGPRs (MFMA A/B frag)
typedef __attribute__((ext_vector_type(4))) float f32x4;    // MFMA C/D frag

__device__ __forceinline__ float bf2f(bf16 v) { return __bfloat162float(v); }

// load 8 contiguous fp32 and round to 8 bf16 (RNE, same as __float2bfloat16 cast kernel)
__device__ __forceinline__ short8 ld8_f32_to_bf16(const float* p) {
  const float4 f0 = ((const float4*)p)[0];
  const float4 f1 = ((const float4*)p)[1];
  short8 s;
  s[0] = (short)__bfloat16_as_ushort(__float2bfloat16(f0.x));
  s[1] = (short)__bfloat16_as_ushort(__float2bfloat16(f0.y));
  s[2] = (short)__bfloat16_as_ushort(__float2bfloat16(f0.z));
  s[3] = (short)__bfloat16_as_ushort(__float2bfloat16(f0.w));
  s[4] = (short)__bfloat16_as_ushort(__float2bfloat16(f1.x));
  s[5] = (short)__bfloat16_as_ushort(__float2bfloat16(f1.y));
  s[6] = (short)__bfloat16_as_ushort(__float2bfloat16(f1.z));
  s[7] = (short)__bfloat16_as_ushort(__float2bfloat16(f1.w));
  return s;
}

// C[m][n] = sum_k A[m][k] * W[n][k]  (both K-contiguous row-major)
// 128x128 tile, 256 threads (4 waves in 2x2, each 64x64 = 4x4 MFMA 16x16x32).
// Staging: register loads -> ds_write_b128 (compiler hoists next-tile global
// loads above current MFMA burst -> latency hidden; global_load_lds regressed
// here, see round-4 post-mortem). A_F32/W_F32: operand is fp32 in global,
// cast to bf16 in-register during staging (folds the cast pass into the GEMM).
// WRITE_S1: fuse chunk sums of bf16(w)^2 into the epilogue.
template <bool A_F32, bool W_F32, bool OUT_BF16, bool WRITE_S1>
__global__ __launch_bounds__(256) void gemm_bt(const void* __restrict__ Av,
                                               const void* __restrict__ Wv,
                                               void* __restrict__ Cout,
                                               float* __restrict__ S1,
                                               int M, int N, int K) {
  __shared__ __align__(16) unsigned short sA[128][32];   // 8 KB
  __shared__ __align__(16) unsigned short sB[128][32];   // 8 KB
  const int tid  = threadIdx.x;
  const int lane = tid & 63;
  const int wave = tid >> 6;
  const int bn = blockIdx.x * 128;
  const int bm = blockIdx.y * 128;
  const int wm = (wave & 1) * 64;
  const int wn = (wave >> 1) * 64;
  const int quad = lane >> 4;
  const int l16  = lane & 15;

  f32x4 acc[4][4] = {};

  // staging map: thread tid covers rows (tid>>2) and (tid>>2)+64, 8 elems at col (tid&3)*8
  const int rowL = tid >> 2;          // 0..63
  const int col8 = (tid & 3) * 8;     // 0,8,16,24

  for (int k0 = 0; k0 < K; k0 += 32) {
    short8 a0, a1, b0, b1;
    if constexpr (A_F32) {
      a0 = ld8_f32_to_bf16((const float*)Av + (size_t)(bm + rowL) * K + (k0 + col8));
      a1 = ld8_f32_to_bf16((const float*)Av + (size_t)(bm + 64 + rowL) * K + (k0 + col8));
    } else {
      a0 = *(const short8*)((const bf16*)Av + (size_t)(bm + rowL) * K + (k0 + col8));
      a1 = *(const short8*)((const bf16*)Av + (size_t)(bm + 64 + rowL) * K + (k0 + col8));
    }
    if constexpr (W_F32) {
      b0 = ld8_f32_to_bf16((const float*)Wv + (size_t)(bn + rowL) * K + (k0 + col8));
      b1 = ld8_f32_to_bf16((const float*)Wv + (size_t)(bn + 64 + rowL) * K + (k0 + col8));
    } else {
      b0 = *(const short8*)((const bf16*)Wv + (size_t)(bn + rowL) * K + (k0 + col8));
      b1 = *(const short8*)((const bf16*)Wv + (size_t)(bn + 64 + rowL) * K + (k0 + col8));
    }
    *(short8*)&sA[rowL][col8]      = a0;
    *(short8*)&sA[64 + rowL][col8] = a1;
    *(short8*)&sB[rowL][col8]      = b0;
    *(short8*)&sB[64 + rowL][col8] = b1;
    __syncthreads();

    short8 af[4], bfv[4];
#pragma unroll
    for (int i = 0; i < 4; i++) af[i]  = *(const short8*)&sA[wm + i * 16 + l16][quad * 8];
#pragma unroll
    for (int j = 0; j < 4; j++) bfv[j] = *(const short8*)&sB[wn + j * 16 + l16][quad * 8];
#pragma unroll
    for (int i = 0; i < 4; i++)
#pragma unroll
      for (int j = 0; j < 4; j++)
        acc[i][j] = __builtin_amdgcn_mfma_f32_16x16x32_bf16(af[i], bfv[j], acc[i][j], 0, 0, 0);
    __syncthreads();
  }

  // C/D layout (HW-verified): col = lane&15, row = (lane>>4)*4 + reg
#pragma unroll
  for (int j = 0; j < 4; j++) {
    const int col = bn + wn + j * 16 + l16;
    float ssum = 0.f;
#pragma unroll
    for (int i = 0; i < 4; i++) {
#pragma unroll
      for (int r = 0; r < 4; r++) {
        const int row = bm + wm + i * 16 + quad * 4 + r;
        if constexpr (OUT_BF16) {
          const bf16 hv = __float2bfloat16(acc[i][j][r]);
          ((bf16*)Cout)[(size_t)row * N + col] = hv;
          if constexpr (WRITE_S1) { const float fv = bf2f(hv); ssum += fv * fv; }
        } else {
          ((float*)Cout)[(size_t)row * N + col] = acc[i][j][r];
        }
      }
    }
    if constexpr (WRITE_S1) {
      // reduce over the 4 quads (same l16 -> same col); rows union = full 64-chunk
      ssum += __shfl_xor(ssum, 16, 64);
      ssum += __shfl_xor(ssum, 32, 64);
      if (quad == 0) {
        const int r0 = bm + wm;           // first row of this wave's chunk
        const int b  = r0 >> 12;          // / Tt
        const int c  = (r0 & (Tt - 1)) >> 6;
        const int h  = col >> 6, d = col & 63;
        S1[(((size_t)(b * NHh + h) * NCH) + c) * HD + d] = ssum;
      }
    }
  }
}

// penalty[b,t] = (phi[b,t] - cumsum(phi)[b,t]/(t+1))^2 ; block-scan per batch
__global__ void phi_penalty_kernel(const float* __restrict__ phi, float* __restrict__ penalty) {
  const int b = blockIdx.x;
  const int tid = threadIdx.x;            // 256
  const int lane = tid & 63, wid = tid >> 6;
  __shared__ float wsum[4];
  __shared__ float carry_s;
  if (tid == 0) carry_s = 0.f;
  __syncthreads();
  for (int r = 0; r < Tt / 256; r++) {
    const int t = r * 256 + tid;
    const float v = phi[b * Tt + t];
    float incl = v;
#pragma unroll
    for (int off = 1; off < 64; off <<= 1) {
      float n = __shfl_up(incl, off, 64);
      if (lane >= off) incl += n;
    }
    if (lane == 63) wsum[wid] = incl;
    __syncthreads();
    float woff = carry_s;
    for (int wpre = 0; wpre < wid; wpre++) woff += wsum[wpre];
    const float csum = woff + incl;
    const float mean = csum / (float)(t + 1);
    const float dphi = v - mean;
    penalty[b * Tt + t] = dphi * dphi;
    __syncthreads();
    if (tid == 0) carry_s += wsum[0] + wsum[1] + wsum[2] + wsum[3];
    __syncthreads();
  }
}

// parallel exclusive prefix over chunks: block (c,bh), lane d sums predecessors
__global__ void prefix_par(const float* __restrict__ S, float* __restrict__ Se) {
  const int c = blockIdx.x, bh = blockIdx.y, d = threadIdx.x;
  const float* p = S + (size_t)bh * NCH * HD + d;
  float run = 0.f;
  for (int cc = 0; cc < c; cc++) run += p[(size_t)cc * HD];
  Se[((size_t)bh * NCH + c) * HD + d] = run;
}

// same for S2, plus SA exclusive prefix via in-wave scan
__global__ void prefix_par_dots(const float* __restrict__ S2, float* __restrict__ S2e,
                                const float* __restrict__ SA, float* __restrict__ SAe) {
  const int c = blockIdx.x, bh = blockIdx.y, d = threadIdx.x;
  const float* p = S2 + (size_t)bh * NCH * HD + d;
  float run = 0.f;
  for (int cc = 0; cc < c; cc++) run += p[(size_t)cc * HD];
  S2e[((size_t)bh * NCH + c) * HD + d] = run;
  // SA: lane d holds chunk d's sum; exclusive via inclusive shfl scan
  const float v = SA[(size_t)bh * NCH + d];
  float incl = v;
#pragma unroll
  for (int off = 1; off < 64; off <<= 1) {
    const float n = __shfl_up(incl, off, 64);
    if (d >= off) incl += n;
  }
  const float mine = __shfl(incl - v, c, 64);
  if (d == 0) SAe[(size_t)bh * NCH + c] = mine;
}

// tssa[b,h,t] = temp[h] * sum_d( w_sq / max(cumsum_t(w_sq),1e-12) )
__global__ void tssa_phase3(const bf16* __restrict__ w, const float* __restrict__ Sex,
                            const float* __restrict__ temp, float* __restrict__ tssa) {
  const int c = blockIdx.x, h = blockIdx.y, b = blockIdx.z, d = threadIdx.x;
  float acc = Sex[(((size_t)(b * NHh + h) * NCH) + c) * HD + d];
  const bf16* wp = w + ((size_t)(b * Tt + c * CHL)) * Dm + h * HD + d;
  const float tv = temp[h];
  float* op = tssa + (size_t)(b * NHh + h) * Tt + c * CHL;
  for (int i = 0; i < CHL; i++) {
    const float v = bf2f(wp[(size_t)i * Dm]);
    const float sq = v * v;
    acc += sq;
    float val = sq / fmaxf(acc, 1e-12f);
#pragma unroll
    for (int off = 32; off > 0; off >>= 1) val += __shfl_xor(val, off, 64);
    if (d == 0) op[i] = tv * val;
  }
}

// softmax over heads; writes fp32 alpha straight into d_out's alpha region
__global__ void softmax_heads(const float* __restrict__ tssa, const float* __restrict__ penalty,
                              const float* __restrict__ gamma, float* __restrict__ alpha_f) {
  const int idx = blockIdx.x * blockDim.x + threadIdx.x;  // over B*T
  const int b = idx >> 12;     // T = 4096
  const int t = idx & 4095;
  const float pen = penalty[idx];
  float sc[NHh];
  float mx = -1e30f;
#pragma unroll
  for (int h = 0; h < NHh; h++) {
    const float s = tssa[((size_t)(b * NHh + h)) * Tt + t] - gamma[h] * pen;
    sc[h] = s;
    mx = fmaxf(mx, s);
  }
  float sum = 0.f;
#pragma unroll
  for (int h = 0; h < NHh; h++) { const float e = expf(sc[h] - mx); sc[h] = e; sum += e; }
  const float inv = 1.f / sum;
#pragma unroll
  for (int h = 0; h < NHh; h++) {
    alpha_f[((size_t)(b * NHh + h)) * Tt + t] = sc[h] * inv;
  }
}

// chunk sums of w_sq*alpha (vec) and alpha (scalar)
__global__ void dots_phase1(const bf16* __restrict__ w, const float* __restrict__ alpha_f,
                            float* __restrict__ S2, float* __restrict__ SA) {
  const int c = blockIdx.x, h = blockIdx.y, b = blockIdx.z, d = threadIdx.x;
  const bf16* wp = w + ((size_t)(b * Tt + c * CHL)) * Dm + h * HD + d;
  const float* ap = alpha_f + (size_t)(b * NHh + h) * Tt + c * CHL;
  float acc = 0.f, acca = 0.f;
  for (int i = 0; i < CHL; i++) {
    const float a = ap[i];
    const float v = bf2f(wp[(size_t)i * Dm]);
    acc += v * v * a;
    acca += a;
  }
  S2[(((size_t)(b * NHh + h) * NCH) + c) * HD + d] = acc;
  if (d == 0) SA[(size_t)(b * NHh + h) * NCH + c] = acca;
}

// y'[b,t,h*64+d] = -w * alpha * min(1/(1+dots), 1e4), bf16
__global__ void y_phase3(const bf16* __restrict__ w, const float* __restrict__ alpha_f,
                         const float* __restrict__ S2ex, const float* __restrict__ SAex,
                         bf16* __restrict__ yprime) {
  const int c = blockIdx.x, h = blockIdx.y, b = blockIdx.z, d = threadIdx.x;
  float accd = S2ex[(((size_t)(b * NHh + h) * NCH) + c) * HD + d];
  float acca = SAex[(size_t)(b * NHh + h) * NCH + c];
  const bf16* wp = w + ((size_t)(b * Tt + c * CHL)) * Dm + h * HD + d;
  const float* ap = alpha_f + (size_t)(b * NHh + h) * Tt + c * CHL;
  bf16* yp = yprime + ((size_t)(b * Tt + c * CHL)) * Dm + h * HD + d;
  for (int i = 0; i < CHL; i++) {
    const float a = ap[i];
    const float v = bf2f(wp[(size_t)i * Dm]);
    const float sq = v * v;
    accd += sq * a;
    acca += a;
    const float dots = accd / (acca + 1e-8f);
    const float attn = fminf(1.f / (1.f + dots), 10000.f);
    yp[(size_t)i * Dm] = __float2bfloat16(-v * a * attn);
  }
}

extern "C" void kernel_launch(void* const* d_in, const int* in_sizes, int n_in,
                              void* d_out, int out_size, void* d_ws, size_t ws_size,
                              hipStream_t stream) {
  // Reference dtypes: ALL inputs float32, outputs (y, alpha) float32.
  const float* x     = (const float*)d_in[0];
  const float* phi   = (const float*)d_in[1];
  const float* Wattn = (const float*)d_in[2];
  const float* Wproj = (const float*)d_in[3];
  const float* gamma = (const float*)d_in[4];
  const float* temp  = (const float*)d_in[5];

  float* y_out    = (float*)d_out;                          // (B,T,D) fp32
  float* alpha_f  = y_out + (size_t)Bb * Tt * Dm;           // (B,NH,T) fp32

  char* ws = (char*)d_ws;
  bf16*  w_bf   = (bf16*)ws;  ws += (size_t)Bb * Tt * Dm * 2;         // 32 MB
  bf16*  yprime = (bf16*)ws;  ws += (size_t)Bb * Tt * Dm * 2;         // 32 MB
  float* tssa   = (float*)ws; ws += (size_t)Bb * NHh * Tt * 4;        // 1 MB
  float* pen    = (float*)ws; ws += (size_t)Bb * Tt * 4;              // 64 KB
  float* S1     = (float*)ws; ws += (size_t)Bb * NHh * NCH * HD * 4;  // 1 MB
  float* S1e    = (float*)ws; ws += (size_t)Bb * NHh * NCH * HD * 4;  // 1 MB
  float* S2     = (float*)ws; ws += (size_t)Bb * NHh * NCH * HD * 4;  // 1 MB
  float* S2e    = (float*)ws; ws += (size_t)Bb * NHh * NCH * HD * 4;  // 1 MB
  float* SA     = (float*)ws; ws += (size_t)Bb * NHh * NCH * 4;       // 16 KB
  float* SAe    = (float*)ws; ws += (size_t)Bb * NHh * NCH * 4;       // 16 KB

  const int M = Bb * Tt, N = Dm, K = Dm;
  dim3 gg(N / 128, M / 128), gb(256);
  dim3 g3(NCH, NHh, Bb), b64(64);
  dim3 gpre(NCH, Bb * NHh);

  // GEMM1: A = x (fp32, cast in staging), W = Wattn (fp32, cast in staging)
  gemm_bt<true, true, true, true><<<gg, gb, 0, stream>>>(x, Wattn, (void*)w_bf, S1, M, N, K);
  phi_penalty_kernel<<<dim3(Bb), dim3(256), 0, stream>>>(phi, pen);
  prefix_par<<<gpre, b64, 0, stream>>>(S1, S1e);
  tssa_phase3<<<g3, b64, 0, stream>>>(w_bf, S1e, temp, tssa);
  softmax_heads<<<dim3(Bb * Tt / 256), dim3(256), 0, stream>>>(tssa, pen, gamma, alpha_f);
  dots_phase1<<<g3, b64, 0, stream>>>(w_bf, alpha_f, S2, SA);
  prefix_par_dots<<<gpre, b64, 0, stream>>>(S2, S2e, SA, SAe);
  y_phase3<<<g3, b64, 0, stream>>>(w_bf, alpha_f, S2e, SAe, yprime);
  // GEMM2: A = yprime (bf16), W = Wproj (fp32, cast in staging), C = fp32 y_out
  gemm_bt<false, true, false, false><<<gg, gb, 0, stream>>>(yprime, Wproj, (void*)y_out, nullptr, M, N, K);
}

// Round 6
// 362.599 us; speedup vs baseline: 1.0913x; 1.0913x over previous
//
#include <hip/hip_runtime.h>
#include <hip/hip_bf16.h>
#include <stdint.h>

// Problem constants (B,T,D,NH from reference)
#define NHh 16
#define Dm  1024
#define HD  64          // head dim = D/NH
#define Bb  4
#define Tt  4096
#define NCH 64          // chunks along T for the two-pass scans
#define CHL 64          // chunk length (NCH*CHL == Tt)

using bf16 = __hip_bfloat16;
typedef __attribute__((ext_vector_type(8))) short short8;   // 8 bf16 in 4 VGPRs (MFMA A/B frag)
typedef __attribute__((ext_vector_type(4))) float f32x4;    // MFMA C/D frag

__device__ __forceinline__ float bf2f(bf16 v) { return __bfloat162float(v); }

// fp32 -> bf16 cast, vectorized; n divisible by 4.
// NOTE (r5 post-mortem): cast-ahead beats cast-in-GEMM — the bf16 scratch is a
// compression cache for operands that get re-fetched ~4x from HBM.
__global__ void cast_f32_to_bf16(const float* __restrict__ in, bf16* __restrict__ out, int n) {
  const int stride = gridDim.x * blockDim.x;
  for (int i = blockIdx.x * blockDim.x + threadIdx.x; i * 4 < n; i += stride) {
    const float4 v = *(const float4*)(in + (size_t)i * 4);
    ushort4 o;
    o.x = __bfloat16_as_ushort(__float2bfloat16(v.x));
    o.y = __bfloat16_as_ushort(__float2bfloat16(v.y));
    o.z = __bfloat16_as_ushort(__float2bfloat16(v.z));
    o.w = __bfloat16_as_ushort(__float2bfloat16(v.w));
    *(ushort4*)(out + (size_t)i * 4) = o;
  }
}

// C[m][n] = sum_k A[m][k] * W[n][k]  (both K-contiguous row-major, bf16)
// 128x128 tile, 256 threads (4 waves in 2x2, each 64x64 = 4x4 MFMA 16x16x32).
// Staging: register loads -> ds_write_b128 (72 us/gemm; global_load_lds and
// fp32 cast-in-staging both regressed — r4/r5 post-mortems).
// WRITE_S1: fuse chunk sums of bf16(w)^2 into the epilogue (each wave's 64-row
// span is exactly one T-chunk).
template <bool OUT_BF16, bool WRITE_S1>
__global__ __launch_bounds__(256) void gemm_bt(const bf16* __restrict__ A,
                                               const bf16* __restrict__ W,
                                               void* __restrict__ Cout,
                                               float* __restrict__ S1,
                                               int M, int N, int K) {
  __shared__ __align__(16) unsigned short sA[128][32];   // 8 KB
  __shared__ __align__(16) unsigned short sB[128][32];   // 8 KB
  const int tid  = threadIdx.x;
  const int lane = tid & 63;
  const int wave = tid >> 6;
  const int bn = blockIdx.x * 128;
  const int bm = blockIdx.y * 128;
  const int wm = (wave & 1) * 64;
  const int wn = (wave >> 1) * 64;
  const int quad = lane >> 4;
  const int l16  = lane & 15;

  f32x4 acc[4][4] = {};

  // staging map: thread tid covers rows (tid>>2) and (tid>>2)+64, 8 bf16 at col (tid&3)*8
  const int rowL = tid >> 2;          // 0..63
  const int col8 = (tid & 3) * 8;     // 0,8,16,24

  for (int k0 = 0; k0 < K; k0 += 32) {
    const uint4 a0 = *(const uint4*)(A + (size_t)(bm + rowL) * K + (k0 + col8));
    const uint4 a1 = *(const uint4*)(A + (size_t)(bm + 64 + rowL) * K + (k0 + col8));
    const uint4 b0 = *(const uint4*)(W + (size_t)(bn + rowL) * K + (k0 + col8));
    const uint4 b1 = *(const uint4*)(W + (size_t)(bn + 64 + rowL) * K + (k0 + col8));
    *(uint4*)&sA[rowL][col8]      = a0;
    *(uint4*)&sA[64 + rowL][col8] = a1;
    *(uint4*)&sB[rowL][col8]      = b0;
    *(uint4*)&sB[64 + rowL][col8] = b1;
    __syncthreads();

    short8 af[4], bfv[4];
#pragma unroll
    for (int i = 0; i < 4; i++) af[i]  = *(const short8*)&sA[wm + i * 16 + l16][quad * 8];
#pragma unroll
    for (int j = 0; j < 4; j++) bfv[j] = *(const short8*)&sB[wn + j * 16 + l16][quad * 8];
#pragma unroll
    for (int i = 0; i < 4; i++)
#pragma unroll
      for (int j = 0; j < 4; j++)
        acc[i][j] = __builtin_amdgcn_mfma_f32_16x16x32_bf16(af[i], bfv[j], acc[i][j], 0, 0, 0);
    __syncthreads();
  }

  // C/D layout (HW-verified): col = lane&15, row = (lane>>4)*4 + reg
#pragma unroll
  for (int j = 0; j < 4; j++) {
    const int col = bn + wn + j * 16 + l16;
    float ssum = 0.f;
#pragma unroll
    for (int i = 0; i < 4; i++) {
#pragma unroll
      for (int r = 0; r < 4; r++) {
        const int row = bm + wm + i * 16 + quad * 4 + r;
        if constexpr (OUT_BF16) {
          const bf16 hv = __float2bfloat16(acc[i][j][r]);
          ((bf16*)Cout)[(size_t)row * N + col] = hv;
          if constexpr (WRITE_S1) { const float fv = bf2f(hv); ssum += fv * fv; }
        } else {
          ((float*)Cout)[(size_t)row * N + col] = acc[i][j][r];
        }
      }
    }
    if constexpr (WRITE_S1) {
      // reduce over the 4 quads (same l16 -> same col); rows union = full 64-chunk
      ssum += __shfl_xor(ssum, 16, 64);
      ssum += __shfl_xor(ssum, 32, 64);
      if (quad == 0) {
        const int r0 = bm + wm;           // first row of this wave's chunk
        const int b  = r0 >> 12;          // / Tt
        const int c  = (r0 & (Tt - 1)) >> 6;
        const int h  = col >> 6, d = col & 63;
        S1[(((size_t)(b * NHh + h) * NCH) + c) * HD + d] = ssum;
      }
    }
  }
}

// penalty[b,t] = (phi[b,t] - cumsum(phi)[b,t]/(t+1))^2 ; block-scan per batch
__global__ void phi_penalty_kernel(const float* __restrict__ phi, float* __restrict__ penalty) {
  const int b = blockIdx.x;
  const int tid = threadIdx.x;            // 256
  const int lane = tid & 63, wid = tid >> 6;
  __shared__ float wsum[4];
  __shared__ float carry_s;
  if (tid == 0) carry_s = 0.f;
  __syncthreads();
  for (int r = 0; r < Tt / 256; r++) {
    const int t = r * 256 + tid;
    const float v = phi[b * Tt + t];
    float incl = v;
#pragma unroll
    for (int off = 1; off < 64; off <<= 1) {
      float n = __shfl_up(incl, off, 64);
      if (lane >= off) incl += n;
    }
    if (lane == 63) wsum[wid] = incl;
    __syncthreads();
    float woff = carry_s;
    for (int wpre = 0; wpre < wid; wpre++) woff += wsum[wpre];
    const float csum = woff + incl;
    const float mean = csum / (float)(t + 1);
    const float dphi = v - mean;
    penalty[b * Tt + t] = dphi * dphi;
    __syncthreads();
    if (tid == 0) carry_s += wsum[0] + wsum[1] + wsum[2] + wsum[3];
    __syncthreads();
  }
}

// Fused middle: per (chunk c, batch b) block of 1024 threads (wave = head).
//  phase A: inline exclusive prefix of S1 over chunks, then within-chunk scan
//           of w_sq -> tssa values into LDS.
//  phase B: softmax over heads (wave 0, lane = t) -> alpha to LDS + global.
//  phase C: dots chunk sums (w re-read L2-warm, alpha from LDS) -> S2, SA.
__global__ __launch_bounds__(1024) void fused_mid(
    const bf16* __restrict__ w, const float* __restrict__ S1,
    const float* __restrict__ pen, const float* __restrict__ gamma,
    const float* __restrict__ temp, float* __restrict__ alpha_f,
    float* __restrict__ S2, float* __restrict__ SA) {
  const int c = blockIdx.x, b = blockIdx.y;
  const int tid = threadIdx.x;
  const int h = tid >> 6, d = tid & 63;

  __shared__ float tssa_s[NHh][CHL];
  __shared__ float alpha_s[NHh][CHL];

  const size_t bh = (size_t)(b * NHh + h);

  // phase A: exclusive prefix of S1 (serial per lane, same order as before)
  const float* s1p = S1 + bh * NCH * HD + d;
  float acc = 0.f;
  for (int cc = 0; cc < c; cc++) acc += s1p[(size_t)cc * HD];

  const bf16* wp = w + ((size_t)(b * Tt + c * CHL)) * Dm + h * HD + d;
  const float tv = temp[h];
  for (int i = 0; i < CHL; i++) {
    const float v = bf2f(wp[(size_t)i * Dm]);
    const float sq = v * v;
    acc += sq;
    float val = sq / fmaxf(acc, 1e-12f);
#pragma unroll
    for (int off = 32; off > 0; off >>= 1) val += __shfl_xor(val, off, 64);
    if (d == 0) tssa_s[h][i] = tv * val;
  }
  __syncthreads();

  // phase B: softmax over heads, lane = t (wave 0 only; tiny)
  if (tid < CHL) {
    const int tg = c * CHL + tid;
    const float pv = pen[b * Tt + tg];
    float sc[NHh];
    float mx = -1e30f;
#pragma unroll
    for (int h2 = 0; h2 < NHh; h2++) {
      const float s = tssa_s[h2][tid] - gamma[h2] * pv;
      sc[h2] = s;
      mx = fmaxf(mx, s);
    }
    float sum = 0.f;
#pragma unroll
    for (int h2 = 0; h2 < NHh; h2++) { const float e = expf(sc[h2] - mx); sc[h2] = e; sum += e; }
    const float inv = 1.f / sum;
#pragma unroll
    for (int h2 = 0; h2 < NHh; h2++) {
      const float a = sc[h2] * inv;
      alpha_s[h2][tid] = a;
      alpha_f[((size_t)(b * NHh + h2)) * Tt + tg] = a;
    }
  }
  __syncthreads();

  // phase C: dots chunk sums
  float acc2 = 0.f, acca = 0.f;
  for (int i = 0; i < CHL; i++) {
    const float a = alpha_s[h][i];
    const float v = bf2f(wp[(size_t)i * Dm]);
    acc2 += v * v * a;
    acca += a;
  }
  S2[(bh * NCH + c) * HD + d] = acc2;
  if (d == 0) SA[bh * NCH + c] = acca;
}

// y'[b,t,h*64+d] = -w * alpha * min(1/(1+dots), 1e4), bf16.
// S2/SA exclusive prefixes inlined (serial per-lane for S2; masked shfl-reduce for SA).
__global__ void y_phase3(const bf16* __restrict__ w, const float* __restrict__ alpha_f,
                         const float* __restrict__ S2, const float* __restrict__ SA,
                         bf16* __restrict__ yprime) {
  const int c = blockIdx.x, h = blockIdx.y, b = blockIdx.z, d = threadIdx.x;
  const size_t bh = (size_t)(b * NHh + h);

  const float* s2p = S2 + bh * NCH * HD + d;
  float accd = 0.f;
  for (int cc = 0; cc < c; cc++) accd += s2p[(size_t)cc * HD];

  float acca = (d < c) ? SA[bh * NCH + d] : 0.f;
#pragma unroll
  for (int off = 32; off > 0; off >>= 1) acca += __shfl_xor(acca, off, 64);

  const bf16* wp = w + ((size_t)(b * Tt + c * CHL)) * Dm + h * HD + d;
  const float* ap = alpha_f + bh * Tt + c * CHL;
  bf16* yp = yprime + ((size_t)(b * Tt + c * CHL)) * Dm + h * HD + d;
  for (int i = 0; i < CHL; i++) {
    const float a = ap[i];
    const float v = bf2f(wp[(size_t)i * Dm]);
    const float sq = v * v;
    accd += sq * a;
    acca += a;
    const float dots = accd / (acca + 1e-8f);
    const float attn = fminf(1.f / (1.f + dots), 10000.f);
    yp[(size_t)i * Dm] = __float2bfloat16(-v * a * attn);
  }
}

extern "C" void kernel_launch(void* const* d_in, const int* in_sizes, int n_in,
                              void* d_out, int out_size, void* d_ws, size_t ws_size,
                              hipStream_t stream) {
  // Reference dtypes: ALL inputs float32, outputs (y, alpha) float32.
  const float* x     = (const float*)d_in[0];
  const float* phi   = (const float*)d_in[1];
  const float* Wattn = (const float*)d_in[2];
  const float* Wproj = (const float*)d_in[3];
  const float* gamma = (const float*)d_in[4];
  const float* temp  = (const float*)d_in[5];

  float* y_out    = (float*)d_out;                          // (B,T,D) fp32
  float* alpha_f  = y_out + (size_t)Bb * Tt * Dm;           // (B,NH,T) fp32

  char* ws = (char*)d_ws;
  bf16*  x_bf   = (bf16*)ws;  ws += (size_t)Bb * Tt * Dm * 2;         // 32 MB
  bf16*  Wa_bf  = (bf16*)ws;  ws += (size_t)Dm * Dm * 2;              // 2 MB
  bf16*  Wp_bf  = (bf16*)ws;  ws += (size_t)Dm * Dm * 2;              // 2 MB
  bf16*  w_bf   = (bf16*)ws;  ws += (size_t)Bb * Tt * Dm * 2;         // 32 MB
  float* pen    = (float*)ws; ws += (size_t)Bb * Tt * 4;              // 64 KB
  float* S1     = (float*)ws; ws += (size_t)Bb * NHh * NCH * HD * 4;  // 1 MB
  float* S2     = (float*)ws; ws += (size_t)Bb * NHh * NCH * HD * 4;  // 1 MB
  float* SA     = (float*)ws; ws += (size_t)Bb * NHh * NCH * 4;       // 16 KB
  bf16*  yprime = x_bf;  // alias: x_bf dead after GEMM1

  const int M = Bb * Tt, N = Dm, K = Dm;
  dim3 gg(N / 128, M / 128), gb(256);
  dim3 g3(NCH, NHh, Bb), b64(64);

  cast_f32_to_bf16<<<dim3(1024), dim3(256), 0, stream>>>(x, x_bf, Bb * Tt * Dm);
  cast_f32_to_bf16<<<dim3(256), dim3(256), 0, stream>>>(Wattn, Wa_bf, Dm * Dm);
  cast_f32_to_bf16<<<dim3(256), dim3(256), 0, stream>>>(Wproj, Wp_bf, Dm * Dm);

  gemm_bt<true, true><<<gg, gb, 0, stream>>>(x_bf, Wa_bf, (void*)w_bf, S1, M, N, K);
  phi_penalty_kernel<<<dim3(Bb), dim3(256), 0, stream>>>(phi, pen);
  fused_mid<<<dim3(NCH, Bb), dim3(1024), 0, stream>>>(w_bf, S1, pen, gamma, temp, alpha_f, S2, SA);
  y_phase3<<<g3, b64, 0, stream>>>(w_bf, alpha_f, S2, SA, yprime);
  gemm_bt<false, false><<<gg, gb, 0, stream>>>(yprime, Wp_bf, (void*)y_out, nullptr, M, N, K);
}

// Round 7
// 350.873 us; speedup vs baseline: 1.1278x; 1.0334x over previous
//
#include <hip/hip_runtime.h>
#include <hip/hip_bf16.h>
#include <stdint.h>

// Problem constants (B,T,D,NH from reference)
#define NHh 16
#define Dm  1024
#define HD  64          // head dim = D/NH
#define Bb  4
#define Tt  4096
#define NCH 64          // chunks along T for the two-pass scans
#define CHL 64          // chunk length (NCH*CHL == Tt)

using bf16 = __hip_bfloat16;
typedef __attribute__((ext_vector_type(8))) short short8;   // 8 bf16 in 4 VGPRs (MFMA A/B frag)
typedef __attribute__((ext_vector_type(4))) float f32x4;    // MFMA C/D frag

__device__ __forceinline__ float bf2f(bf16 v) { return __bfloat162float(v); }
__device__ __forceinline__ float frcp(float x) { return __builtin_amdgcn_rcpf(x); }

// unpack 4 bf16 (packed in uint2) -> 4 fp32 (exact: bf16 is f32's high half)
__device__ __forceinline__ void unpack4(uint2 u, float& v0, float& v1, float& v2, float& v3) {
  v0 = __uint_as_float(u.x << 16);
  v1 = __uint_as_float(u.x & 0xffff0000u);
  v2 = __uint_as_float(u.y << 16);
  v3 = __uint_as_float(u.y & 0xffff0000u);
}

// one kernel casting x, W_attn, W_proj to bf16 (r5 lesson: cast-ahead is a
// compression cache for re-fetched operands; merged to cut launch count)
__global__ void cast_all(const float* __restrict__ x, const float* __restrict__ Wa,
                         const float* __restrict__ Wp, bf16* __restrict__ x_bf,
                         bf16* __restrict__ Wa_bf, bf16* __restrict__ Wp_bf) {
  const float* src; bf16* dst; size_t nq, base_blk, nblk;
  if (blockIdx.x < 2048)      { src = x;  dst = x_bf;  nq = (size_t)Bb * Tt * Dm / 4; base_blk = 0;    nblk = 2048; }
  else if (blockIdx.x < 2112) { src = Wa; dst = Wa_bf; nq = (size_t)Dm * Dm / 4;      base_blk = 2048; nblk = 64; }
  else                        { src = Wp; dst = Wp_bf; nq = (size_t)Dm * Dm / 4;      base_blk = 2112; nblk = 64; }
  const size_t stride = nblk * blockDim.x;
  for (size_t i = (blockIdx.x - base_blk) * blockDim.x + threadIdx.x; i < nq; i += stride) {
    const float4 v = *(const float4*)(src + i * 4);
    ushort4 o;
    o.x = __bfloat16_as_ushort(__float2bfloat16(v.x));
    o.y = __bfloat16_as_ushort(__float2bfloat16(v.y));
    o.z = __bfloat16_as_ushort(__float2bfloat16(v.z));
    o.w = __bfloat16_as_ushort(__float2bfloat16(v.w));
    *(ushort4*)(dst + i * 4) = o;
  }
}

// C[m][n] = sum_k A[m][k] * W[n][k]  (both K-contiguous row-major, bf16)
// 128x128 tile, 256 threads (4 waves in 2x2, each 64x64 = 4x4 MFMA 16x16x32).
// Staging: register loads -> ds_write_b128 (72 us/gemm; global_load_lds and
// fp32 cast-in-staging both regressed — r4/r5 post-mortems).
// WRITE_S1: fuse chunk sums of bf16(w)^2 into epilogue; S1 layout [b][c][1024].
template <bool OUT_BF16, bool WRITE_S1>
__global__ __launch_bounds__(256) void gemm_bt(const bf16* __restrict__ A,
                                               const bf16* __restrict__ W,
                                               void* __restrict__ Cout,
                                               float* __restrict__ S1,
                                               int M, int N, int K) {
  __shared__ __align__(16) unsigned short sA[128][32];   // 8 KB
  __shared__ __align__(16) unsigned short sB[128][32];   // 8 KB
  const int tid  = threadIdx.x;
  const int lane = tid & 63;
  const int wave = tid >> 6;
  const int bn = blockIdx.x * 128;
  const int bm = blockIdx.y * 128;
  const int wm = (wave & 1) * 64;
  const int wn = (wave >> 1) * 64;
  const int quad = lane >> 4;
  const int l16  = lane & 15;

  f32x4 acc[4][4] = {};

  const int rowL = tid >> 2;          // 0..63
  const int col8 = (tid & 3) * 8;     // 0,8,16,24

  for (int k0 = 0; k0 < K; k0 += 32) {
    const uint4 a0 = *(const uint4*)(A + (size_t)(bm + rowL) * K + (k0 + col8));
    const uint4 a1 = *(const uint4*)(A + (size_t)(bm + 64 + rowL) * K + (k0 + col8));
    const uint4 b0 = *(const uint4*)(W + (size_t)(bn + rowL) * K + (k0 + col8));
    const uint4 b1 = *(const uint4*)(W + (size_t)(bn + 64 + rowL) * K + (k0 + col8));
    *(uint4*)&sA[rowL][col8]      = a0;
    *(uint4*)&sA[64 + rowL][col8] = a1;
    *(uint4*)&sB[rowL][col8]      = b0;
    *(uint4*)&sB[64 + rowL][col8] = b1;
    __syncthreads();

    short8 af[4], bfv[4];
#pragma unroll
    for (int i = 0; i < 4; i++) af[i]  = *(const short8*)&sA[wm + i * 16 + l16][quad * 8];
#pragma unroll
    for (int j = 0; j < 4; j++) bfv[j] = *(const short8*)&sB[wn + j * 16 + l16][quad * 8];
#pragma unroll
    for (int i = 0; i < 4; i++)
#pragma unroll
      for (int j = 0; j < 4; j++)
        acc[i][j] = __builtin_amdgcn_mfma_f32_16x16x32_bf16(af[i], bfv[j], acc[i][j], 0, 0, 0);
    __syncthreads();
  }

  // C/D layout (HW-verified): col = lane&15, row = (lane>>4)*4 + reg
#pragma unroll
  for (int j = 0; j < 4; j++) {
    const int col = bn + wn + j * 16 + l16;
    float ssum = 0.f;
#pragma unroll
    for (int i = 0; i < 4; i++) {
#pragma unroll
      for (int r = 0; r < 4; r++) {
        const int row = bm + wm + i * 16 + quad * 4 + r;
        if constexpr (OUT_BF16) {
          const bf16 hv = __float2bfloat16(acc[i][j][r]);
          ((bf16*)Cout)[(size_t)row * N + col] = hv;
          if constexpr (WRITE_S1) { const float fv = bf2f(hv); ssum += fv * fv; }
        } else {
          ((float*)Cout)[(size_t)row * N + col] = acc[i][j][r];
        }
      }
    }
    if constexpr (WRITE_S1) {
      ssum += __shfl_xor(ssum, 16, 64);
      ssum += __shfl_xor(ssum, 32, 64);
      if (quad == 0) {
        const int r0 = bm + wm;           // first row of this wave's chunk
        const int b  = r0 >> 12;          // / Tt
        const int c  = (r0 & (Tt - 1)) >> 6;
        S1[((size_t)(b * NCH + c)) * Dm + col] = ssum;
      }
    }
  }
}

// penalty[b,t] = (phi[b,t] - cumsum(phi)[b,t]/(t+1))^2 ; block-scan per batch
__global__ void phi_penalty_kernel(const float* __restrict__ phi, float* __restrict__ penalty) {
  const int b = blockIdx.x;
  const int tid = threadIdx.x;            // 256
  const int lane = tid & 63, wid = tid >> 6;
  __shared__ float wsum[4];
  __shared__ float carry_s;
  if (tid == 0) carry_s = 0.f;
  __syncthreads();
  for (int r = 0; r < Tt / 256; r++) {
    const int t = r * 256 + tid;
    const float v = phi[b * Tt + t];
    float incl = v;
#pragma unroll
    for (int off = 1; off < 64; off <<= 1) {
      float n = __shfl_up(incl, off, 64);
      if (lane >= off) incl += n;
    }
    if (lane == 63) wsum[wid] = incl;
    __syncthreads();
    float woff = carry_s;
    for (int wpre = 0; wpre < wid; wpre++) woff += wsum[wpre];
    const float csum = woff + incl;
    const float mean = csum / (float)(t + 1);
    const float dphi = v - mean;
    penalty[b * Tt + t] = dphi * dphi;
    __syncthreads();
    if (tid == 0) carry_s += wsum[0] + wsum[1] + wsum[2] + wsum[3];
    __syncthreads();
  }
}

// Fused middle, vectorized: block (c,b), 256 threads, thread owns 4 consecutive d.
//  A: inline S1 exclusive prefix (float4, coalesced) + within-chunk scan of w_sq
//     -> tssa to LDS (in-thread sum of 4 + 4-step shfl over 16 lanes).
//  B: softmax over heads (64 lanes, lane = t) -> alpha LDS + global.
//  C: dots chunk sums (w re-read L2-warm) -> S2 [b][c][1024], SA [b][c][16].
__global__ __launch_bounds__(256) void scan_mid(
    const bf16* __restrict__ w, const float* __restrict__ S1,
    const float* __restrict__ pen, const float* __restrict__ gamma,
    const float* __restrict__ temp, float* __restrict__ alpha_f,
    float* __restrict__ S2, float* __restrict__ SA) {
  const int c = blockIdx.x, b = blockIdx.y;
  const int tid = threadIdx.x;
  const int d0 = tid * 4;
  const int h = tid >> 4;              // 16 threads per head

  __shared__ float tssa_s[NHh][CHL];
  __shared__ float alpha_s[NHh][CHL];

  // inline exclusive prefix of S1 over chunks
  float4 dn = make_float4(0.f, 0.f, 0.f, 0.f);
  const float* s1p = S1 + (size_t)b * NCH * Dm + d0;
  for (int cc = 0; cc < c; cc++) {
    const float4 v = *(const float4*)(s1p + (size_t)cc * Dm);
    dn.x += v.x; dn.y += v.y; dn.z += v.z; dn.w += v.w;
  }

  const bf16* wrow = w + ((size_t)(b * Tt + c * CHL)) * Dm + d0;
  const float tv = temp[h];

  // phase A: tssa
  for (int i = 0; i < CHL; i++) {
    float v0, v1, v2, v3;
    unpack4(*(const uint2*)(wrow + (size_t)i * Dm), v0, v1, v2, v3);
    const float s0 = v0 * v0, s1 = v1 * v1, s2 = v2 * v2, s3 = v3 * v3;
    dn.x += s0; dn.y += s1; dn.z += s2; dn.w += s3;
    float val = s0 * frcp(fmaxf(dn.x, 1e-12f)) + s1 * frcp(fmaxf(dn.y, 1e-12f))
              + s2 * frcp(fmaxf(dn.z, 1e-12f)) + s3 * frcp(fmaxf(dn.w, 1e-12f));
    val += __shfl_xor(val, 1, 64);
    val += __shfl_xor(val, 2, 64);
    val += __shfl_xor(val, 4, 64);
    val += __shfl_xor(val, 8, 64);
    if ((tid & 15) == 0) tssa_s[h][i] = tv * val;
  }
  __syncthreads();

  // phase B: softmax over heads, lane = t (first wave only)
  if (tid < CHL) {
    const int tg = c * CHL + tid;
    const float pv = pen[b * Tt + tg];
    float sc[NHh];
    float mx = -1e30f;
#pragma unroll
    for (int h2 = 0; h2 < NHh; h2++) {
      const float s = tssa_s[h2][tid] - gamma[h2] * pv;
      sc[h2] = s;
      mx = fmaxf(mx, s);
    }
    float sum = 0.f;
#pragma unroll
    for (int h2 = 0; h2 < NHh; h2++) { const float e = expf(sc[h2] - mx); sc[h2] = e; sum += e; }
    const float inv = 1.f / sum;
#pragma unroll
    for (int h2 = 0; h2 < NHh; h2++) {
      const float a = sc[h2] * inv;
      alpha_s[h2][tid] = a;
      alpha_f[((size_t)(b * NHh + h2)) * Tt + tg] = a;
    }
  }
  __syncthreads();

  // phase C: dots chunk sums
  float4 a2 = make_float4(0.f, 0.f, 0.f, 0.f);
  float aa = 0.f;
  for (int i = 0; i < CHL; i++) {
    float v0, v1, v2, v3;
    unpack4(*(const uint2*)(wrow + (size_t)i * Dm), v0, v1, v2, v3);
    const float a = alpha_s[h][i];
    a2.x += v0 * v0 * a; a2.y += v1 * v1 * a; a2.z += v2 * v2 * a; a2.w += v3 * v3 * a;
    aa += a;
  }
  *(float4*)(S2 + ((size_t)(b * NCH + c)) * Dm + d0) = a2;
  if ((tid & 15) == 0) SA[((size_t)(b * NCH + c)) * NHh + h] = aa;
}

// y'[b,t,dm] = -w * alpha * min(1/(1+dots), 1e4), bf16; vectorized 4 d/thread.
// S2/SA exclusive prefixes inlined (coalesced float4 / broadcast scalar).
__global__ __launch_bounds__(256) void y_phase4(
    const bf16* __restrict__ w, const float* __restrict__ alpha_f,
    const float* __restrict__ S2, const float* __restrict__ SA,
    bf16* __restrict__ yprime) {
  const int c = blockIdx.x, b = blockIdx.y;
  const int tid = threadIdx.x;
  const int d0 = tid * 4;
  const int h = tid >> 4;

  __shared__ float alpha_s[NHh][CHL];

  float4 accd = make_float4(0.f, 0.f, 0.f, 0.f);
  const float* s2p = S2 + (size_t)b * NCH * Dm + d0;
  for (int cc = 0; cc < c; cc++) {
    const float4 v = *(const float4*)(s2p + (size_t)cc * Dm);
    accd.x += v.x; accd.y += v.y; accd.z += v.z; accd.w += v.w;
  }
  float acca = 0.f;
  const float* sap = SA + (size_t)b * NCH * NHh + h;
  for (int cc = 0; cc < c; cc++) acca += sap[(size_t)cc * NHh];

  // stage this chunk's alpha into LDS: thread -> (h2 = tid>>4, t4 = (tid&15)*4)
  {
    const int h2 = tid >> 4, t4 = (tid & 15) * 4;
    const float4 av = *(const float4*)(alpha_f + ((size_t)(b * NHh + h2)) * Tt + c * CHL + t4);
    alpha_s[h2][t4] = av.x; alpha_s[h2][t4 + 1] = av.y;
    alpha_s[h2][t4 + 2] = av.z; alpha_s[h2][t4 + 3] = av.w;
  }
  __syncthreads();

  const bf16* wrow = w + ((size_t)(b * Tt + c * CHL)) * Dm + d0;
  bf16* yrow = yprime + ((size_t)(b * Tt + c * CHL)) * Dm + d0;
  for (int i = 0; i < CHL; i++) {
    float v0, v1, v2, v3;
    unpack4(*(const uint2*)(wrow + (size_t)i * Dm), v0, v1, v2, v3);
    const float a = alpha_s[h][i];
    accd.x += v0 * v0 * a; accd.y += v1 * v1 * a;
    accd.z += v2 * v2 * a; accd.w += v3 * v3 * a;
    acca += a;
    const float rden = frcp(acca + 1e-8f);
    const float at0 = fminf(frcp(1.f + accd.x * rden), 10000.f);
    const float at1 = fminf(frcp(1.f + accd.y * rden), 10000.f);
    const float at2 = fminf(frcp(1.f + accd.z * rden), 10000.f);
    const float at3 = fminf(frcp(1.f + accd.w * rden), 10000.f);
    ushort4 o;
    o.x = __bfloat16_as_ushort(__float2bfloat16(-v0 * a * at0));
    o.y = __bfloat16_as_ushort(__float2bfloat16(-v1 * a * at1));
    o.z = __bfloat16_as_ushort(__float2bfloat16(-v2 * a * at2));
    o.w = __bfloat16_as_ushort(__float2bfloat16(-v3 * a * at3));
    *(ushort4*)(yrow + (size_t)i * Dm) = o;
  }
}

extern "C" void kernel_launch(void* const* d_in, const int* in_sizes, int n_in,
                              void* d_out, int out_size, void* d_ws, size_t ws_size,
                              hipStream_t stream) {
  // Reference dtypes: ALL inputs float32, outputs (y, alpha) float32.
  const float* x     = (const float*)d_in[0];
  const float* phi   = (const float*)d_in[1];
  const float* Wattn = (const float*)d_in[2];
  const float* Wproj = (const float*)d_in[3];
  const float* gamma = (const float*)d_in[4];
  const float* temp  = (const float*)d_in[5];

  float* y_out    = (float*)d_out;                          // (B,T,D) fp32
  float* alpha_f  = y_out + (size_t)Bb * Tt * Dm;           // (B,NH,T) fp32

  char* ws = (char*)d_ws;
  bf16*  x_bf   = (bf16*)ws;  ws += (size_t)Bb * Tt * Dm * 2;         // 32 MB
  bf16*  Wa_bf  = (bf16*)ws;  ws += (size_t)Dm * Dm * 2;              // 2 MB
  bf16*  Wp_bf  = (bf16*)ws;  ws += (size_t)Dm * Dm * 2;              // 2 MB
  bf16*  w_bf   = (bf16*)ws;  ws += (size_t)Bb * Tt * Dm * 2;         // 32 MB
  float* pen    = (float*)ws; ws += (size_t)Bb * Tt * 4;              // 64 KB
  float* S1     = (float*)ws; ws += (size_t)Bb * NCH * Dm * 4;        // 1 MB
  float* S2     = (float*)ws; ws += (size_t)Bb * NCH * Dm * 4;        // 1 MB
  float* SA     = (float*)ws; ws += (size_t)Bb * NCH * NHh * 4;       // 16 KB
  bf16*  yprime = x_bf;  // alias: x_bf dead after GEMM1

  const int M = Bb * Tt, N = Dm, K = Dm;
  dim3 gg(N / 128, M / 128), gb(256);
  dim3 gcb(NCH, Bb);

  cast_all<<<dim3(2176), dim3(256), 0, stream>>>(x, Wattn, Wproj, x_bf, Wa_bf, Wp_bf);
  gemm_bt<true, true><<<gg, gb, 0, stream>>>(x_bf, Wa_bf, (void*)w_bf, S1, M, N, K);
  phi_penalty_kernel<<<dim3(Bb), dim3(256), 0, stream>>>(phi, pen);
  scan_mid<<<gcb, dim3(256), 0, stream>>>(w_bf, S1, pen, gamma, temp, alpha_f, S2, SA);
  y_phase4<<<gcb, dim3(256), 0, stream>>>(w_bf, alpha_f, S2, SA, yprime);
  gemm_bt<false, false><<<gg, gb, 0, stream>>>(yprime, Wp_bf, (void*)y_out, nullptr, M, N, K);
}